// Round 5
// baseline (1120.210 us; speedup 1.0000x reference)
//
#include <hip/hip_runtime.h>
#include <hip/hip_bf16.h>

using u16 = unsigned short;
typedef __bf16 bf16x8 __attribute__((ext_vector_type(8)));
typedef float f32x4 __attribute__((ext_vector_type(4)));
typedef u16 u16x8 __attribute__((ext_vector_type(8)));
typedef u16 u16x4 __attribute__((ext_vector_type(4)));

constexpr int T_SEQ = 2048;
constexpr int HID   = 4096;
constexpr int NH    = 32;
constexpr int NKV   = 8;
constexpr int HD    = 128;
constexpr int QKVN  = 6144;   // 32*128 + 2*8*128

__device__ __forceinline__ u16 f2b(float x) {
  return __builtin_bit_cast(u16, __float2bfloat16(x));
}
__device__ __forceinline__ float b2f(u16 u) {
  return __builtin_bit_cast(float, (unsigned int)u << 16);
}
__device__ __forceinline__ bf16x8 load8(const u16* p) {
  return __builtin_bit_cast(bf16x8, *reinterpret_cast<const u16x8*>(p));
}
__device__ __forceinline__ f32x4 mfma16(bf16x8 a, bf16x8 b, f32x4 c) {
  return __builtin_amdgcn_mfma_f32_16x16x32_bf16(a, b, c, 0, 0, 0);
}

// ---------------- cast fp32 -> bf16 (vectorized) ----------------
__global__ __launch_bounds__(256) void k_cast_bf16(const float* __restrict__ in,
                                                   u16* __restrict__ out, int n4) {
  int i = blockIdx.x * 256 + threadIdx.x;
  if (i < n4) {
    float4 v = reinterpret_cast<const float4*>(in)[i];
    u16x4 o;
    o.x = f2b(v.x); o.y = f2b(v.y); o.z = f2b(v.z); o.w = f2b(v.w);
    reinterpret_cast<u16x4*>(out)[i] = o;
  }
}

// ---------------- transpose + cast: in[R][C] fp32 -> out[C][R] bf16 ----------------
__global__ __launch_bounds__(256) void k_transpose_cast(const float* __restrict__ in,
                                                        u16* __restrict__ out,
                                                        int R, int C) {
  __shared__ float tile[32][33];
  int cc = blockIdx.x << 5, rr = blockIdx.y << 5;
  int lx = threadIdx.x & 31, ly = threadIdx.x >> 5;
#pragma unroll
  for (int i = 0; i < 32; i += 8)
    tile[ly + i][lx] = in[(size_t)(rr + ly + i) * C + cc + lx];
  __syncthreads();
#pragma unroll
  for (int i = 0; i < 32; i += 8)
    out[(size_t)(cc + ly + i) * R + rr + lx] = f2b(tile[lx][ly + i]);
}

// ---------------- bf16 GEMM: C[M][N] = A[M][K] * B[N][K]^T ----------------
// 128x128 tile, BK=32, 4 waves (2x2 of 64x64), global_load_lds w16,
// XOR k-slot swizzle: LDS[row][slot] holds k-slot (slot ^ ((row>>1)&3)).
template <int N, int K, typename OutT>
__global__ __launch_bounds__(256) void k_gemm_bt(const u16* __restrict__ A,
                                                 const u16* __restrict__ B,
                                                 OutT* __restrict__ C) {
  __shared__ u16 lA[128 * 32];
  __shared__ u16 lB[128 * 32];
  const int tid = threadIdx.x;
  const int wid = tid >> 6, lane = tid & 63;
  const int row0 = blockIdx.y << 7, col0 = blockIdx.x << 7;
  const int wr = wid >> 1, wc = wid & 1;
  const int g = lane >> 4, c = lane & 15;

  f32x4 acc[4][4] = {};

  const int r_st = lane >> 2;      // row within 16-row wave chunk
  const int slot_st = lane & 3;    // 16B slot within 64B row

  const int rA0 = wr * 64 + c;
  const int rB0 = wc * 64 + c;
  const int swzA = (rA0 >> 1) & 3;  // invariant under +16 row steps
  const int swzB = (rB0 >> 1) & 3;

  for (int kt = 0; kt < K / 32; ++kt) {
    const int kk = kt * 32;
#pragma unroll
    for (int i = 0; i < 2; ++i) {
      int r = wid * 16 + i * 64 + r_st;
      int s = slot_st ^ ((r >> 1) & 3);
      const u16* ga = A + (size_t)(row0 + r) * K + kk + s * 8;
      const u16* gb = B + (size_t)(col0 + r) * K + kk + s * 8;
      char* la = (char*)lA + wid * 1024 + i * 4096;  // wave-uniform base
      char* lb = (char*)lB + wid * 1024 + i * 4096;
      __builtin_amdgcn_global_load_lds((const __attribute__((address_space(1))) void*)ga,
                                       (__attribute__((address_space(3))) void*)la, 16, 0, 0);
      __builtin_amdgcn_global_load_lds((const __attribute__((address_space(1))) void*)gb,
                                       (__attribute__((address_space(3))) void*)lb, 16, 0, 0);
    }
    __syncthreads();

    bf16x8 af[4], bfr[4];
#pragma unroll
    for (int m = 0; m < 4; ++m) {
      int row = rA0 + m * 16;
      af[m] = load8(lA + row * 32 + (g ^ swzA) * 8);
    }
#pragma unroll
    for (int n = 0; n < 4; ++n) {
      int row = rB0 + n * 16;
      bfr[n] = load8(lB + row * 32 + (g ^ swzB) * 8);
    }
#pragma unroll
    for (int m = 0; m < 4; ++m)
#pragma unroll
      for (int n = 0; n < 4; ++n)
        acc[m][n] = mfma16(af[m], bfr[n], acc[m][n]);
    __syncthreads();
  }

  // epilogue: D layout col=lane&15, row=(lane>>4)*4+reg  (m89-verified)
#pragma unroll
  for (int m = 0; m < 4; ++m) {
    int grow0 = row0 + wr * 64 + m * 16 + g * 4;
#pragma unroll
    for (int n = 0; n < 4; ++n) {
      int gcol = col0 + wc * 64 + n * 16 + c;
#pragma unroll
      for (int j = 0; j < 4; ++j) {
        float v = acc[m][n][j];
        if constexpr (sizeof(OutT) == 2)
          C[(size_t)(grow0 + j) * N + gcol] = f2b(v);
        else
          C[(size_t)(grow0 + j) * N + gcol] = v;
      }
    }
  }
}

// ---------------- fused per-head RMSNorm + RoPE + scale, qkv split ----------------
__global__ __launch_bounds__(256) void k_normrope(const u16* __restrict__ qkv,
                                                  const int* __restrict__ pos,
                                                  const float* __restrict__ qw,
                                                  const float* __restrict__ kw,
                                                  u16* __restrict__ qo,
                                                  u16* __restrict__ ko,
                                                  u16* __restrict__ vo) {
  int t = blockIdx.x;
  int wid = threadIdx.x >> 6, lane = threadIdx.x & 63;
  int h = blockIdx.y * 4 + wid;  // 0..47
  const u16* src = qkv + (size_t)t * QKVN + h * HD;
  float x1 = b2f(src[lane]), x2 = b2f(src[lane + 64]);
  float ss = x1 * x1 + x2 * x2;
#pragma unroll
  for (int m = 1; m < 64; m <<= 1) ss += __shfl_xor(ss, m);
  float sc = rsqrtf(ss * (1.0f / HD) + 1e-6f);
  if (h < 40) {
    const float* w = (h < NH) ? qw : kw;
    float y1 = x1 * sc * w[lane], y2 = x2 * sc * w[lane + 64];
    float p = (float)pos[t];
    // inv_freq = 10000^(-lane/64) = exp2(-lane * log2(10000)/64)
    float inv = exp2f((float)lane * (-13.287712379549449f / 64.0f));
    float ang = p * inv;
    float sn, cs;
    sincosf(ang, &sn, &cs);
    float o1 = y1 * cs - y2 * sn;
    float o2 = y2 * cs + y1 * sn;
    if (h < NH) {
      o1 *= 0.08838834764831845f;  // fold 1/sqrt(128) into q
      o2 *= 0.08838834764831845f;
      u16* dst = qo + ((size_t)t * NH + h) * HD;
      dst[lane] = f2b(o1);
      dst[lane + 64] = f2b(o2);
    } else {
      u16* dst = ko + ((size_t)t * NKV + (h - NH)) * HD;
      dst[lane] = f2b(o1);
      dst[lane + 64] = f2b(o2);
    }
  } else {
    u16* dst = vo + ((size_t)t * NKV + (h - 40)) * HD;
    dst[lane] = f2b(x1);
    dst[lane + 64] = f2b(x2);
  }
}

// ---------------- V transpose: vb[T][NKV][HD] -> vt[NKV][HD][T] ----------------
__global__ __launch_bounds__(256) void k_transpose_v(const u16* __restrict__ vb,
                                                     u16* __restrict__ vt) {
  __shared__ u16 tile[32][33];
  int tt = blockIdx.x << 5, dd = blockIdx.y << 5, h = blockIdx.z;
  int lx = threadIdx.x & 31, ly = threadIdx.x >> 5;
#pragma unroll
  for (int i = 0; i < 32; i += 8)
    tile[ly + i][lx] = vb[((size_t)(tt + ly + i) * NKV + h) * HD + dd + lx];
  __syncthreads();
#pragma unroll
  for (int i = 0; i < 32; i += 8)
    vt[((size_t)h * HD + dd + ly + i) * T_SEQ + tt + lx] = tile[lx][ly + i];
}

// ---------------- flash attention v2: swapped QK^T, in-register softmax ----------------
// 4 waves/block; each wave owns one 16-row q-tile; KVBLK=64.
// S^T via mfma(K,Q): lane(g,c) reg j of s[tt] = S[k=kvb+tt*16+4g+j][q=qb0+c].
// Softmax state (m,l) per lane for q=qb0+c (replicated across g).
// PV: P slots pair with V slots {4g+j, 16+4g+j} (slot-consistency cancellation).
__global__ __launch_bounds__(256) void k_attn(const u16* __restrict__ qb,
                                              const u16* __restrict__ kbp,
                                              const u16* __restrict__ vt,
                                              u16* __restrict__ out) {
  const int wid = threadIdx.x >> 6, lane = threadIdx.x & 63;
  const int h = blockIdx.y, hk = h >> 2;
  const int qb0 = (blockIdx.x * 4 + wid) * 16;
  const int g = lane >> 4, c = lane & 15;

  // Q fragment (B-operand): B[col=q=c][k-slot (g,j)]
  bf16x8 qf[4];
  const u16* qrow = qb + ((size_t)(qb0 + c) * NH + h) * HD;
#pragma unroll
  for (int kc = 0; kc < 4; ++kc) qf[kc] = load8(qrow + kc * 32 + g * 8);

  f32x4 accO[8] = {};          // accO[c2][j] = O[q=qb0+4g+j][d=c2*16+c]
  float m_ = -1e30f, l_ = 0.f; // running max/sum for q = qb0 + c

  const u16* vtb = vt + (size_t)hk * HD * T_SEQ;
  const int ntiles = qb0 / 64 + 1;
  const int tq = qb0 + c;

  for (int kt = 0; kt < ntiles; ++kt) {
    const int kvb = kt * 64;
    f32x4 s[4];
#pragma unroll
    for (int tt = 0; tt < 4; ++tt) {
      const u16* krow = kbp + ((size_t)(kvb + tt * 16 + c) * NKV + hk) * HD;
      f32x4 st = {0.f, 0.f, 0.f, 0.f};
#pragma unroll
      for (int kc = 0; kc < 4; ++kc)
        st = mfma16(load8(krow + kc * 32 + g * 8), qf[kc], st);
      s[tt] = st;
    }
    // causal mask + row max (q fixed per lane)
    float vmax = -1e30f;
#pragma unroll
    for (int tt = 0; tt < 4; ++tt)
#pragma unroll
      for (int j = 0; j < 4; ++j) {
        int tk = kvb + tt * 16 + 4 * g + j;
        float v = (tk <= tq) ? s[tt][j] : -1e30f;
        s[tt][j] = v;
        vmax = fmaxf(vmax, v);
      }
    vmax = fmaxf(vmax, __shfl_xor(vmax, 16));
    vmax = fmaxf(vmax, __shfl_xor(vmax, 32));
    float mn = fmaxf(m_, vmax);
    float a = __expf(m_ - mn);
    float ps = 0.f;
#pragma unroll
    for (int tt = 0; tt < 4; ++tt)
#pragma unroll
      for (int j = 0; j < 4; ++j) {
        float p = __expf(s[tt][j] - mn);
        s[tt][j] = p;
        ps += p;
      }
    ps += __shfl_xor(ps, 16);
    ps += __shfl_xor(ps, 32);
    l_ = l_ * a + ps;
    m_ = mn;

    // broadcast rescale factor to accO's q-indexing (q = 4g+j lives at lane c=4g+j)
    float aq[4];
#pragma unroll
    for (int j = 0; j < 4; ++j) aq[j] = __shfl(a, 20 * g + j);
#pragma unroll
    for (int c2 = 0; c2 < 8; ++c2)
#pragma unroll
      for (int j = 0; j < 4; ++j) accO[c2][j] *= aq[j];

    // pack P^T into two A-fragments: frag0 = k[0..31], frag1 = k[32..63]
    u16x8 p0u, p1u;
#pragma unroll
    for (int j = 0; j < 4; ++j) {
      p0u[j]     = f2b(s[0][j]);
      p0u[j + 4] = f2b(s[1][j]);
      p1u[j]     = f2b(s[2][j]);
      p1u[j + 4] = f2b(s[3][j]);
    }
    bf16x8 p0 = __builtin_bit_cast(bf16x8, p0u);
    bf16x8 p1 = __builtin_bit_cast(bf16x8, p1u);

    // PV: V slots must match P's k placement: {4g+j} and {16+4g+j} (+32 for frag1)
#pragma unroll
    for (int c2 = 0; c2 < 8; ++c2) {
      const u16* vcol = vtb + (size_t)(c2 * 16 + c) * T_SEQ + kvb + 4 * g;
      u16x4 va = *reinterpret_cast<const u16x4*>(vcol);
      u16x4 vb4 = *reinterpret_cast<const u16x4*>(vcol + 16);
      u16x4 vc4 = *reinterpret_cast<const u16x4*>(vcol + 32);
      u16x4 vd = *reinterpret_cast<const u16x4*>(vcol + 48);
      u16x8 v0u, v1u;
#pragma unroll
      for (int j = 0; j < 4; ++j) {
        v0u[j] = va[j]; v0u[j + 4] = vb4[j];
        v1u[j] = vc4[j]; v1u[j + 4] = vd[j];
      }
      accO[c2] = mfma16(p0, __builtin_bit_cast(bf16x8, v0u), accO[c2]);
      accO[c2] = mfma16(p1, __builtin_bit_cast(bf16x8, v1u), accO[c2]);
    }
  }

  // epilogue: divide by l (q = 4g+j indexing via shuffle) and store
  float lq[4];
#pragma unroll
  for (int j = 0; j < 4; ++j) lq[j] = 1.0f / __shfl(l_, 20 * g + j);
#pragma unroll
  for (int c2 = 0; c2 < 8; ++c2)
#pragma unroll
    for (int j = 0; j < 4; ++j) {
      float o = accO[c2][j] * lq[j];
      out[(size_t)(qb0 + 4 * g + j) * HID + h * HD + c2 * 16 + c] = f2b(o);
    }
}

// ---------------- launch ----------------
extern "C" void kernel_launch(void* const* d_in, const int* in_sizes, int n_in,
                              void* d_out, int out_size, void* d_ws, size_t ws_size,
                              hipStream_t stream) {
  (void)in_sizes; (void)n_in; (void)out_size; (void)ws_size;
  const float* x      = (const float*)d_in[0];
  const int*   pos    = (const int*)d_in[1];
  const float* qkv_w  = (const float*)d_in[2];
  const float* qnw    = (const float*)d_in[3];
  const float* knw    = (const float*)d_in[4];
  const float* ow     = (const float*)d_in[5];
  float* out = (float*)d_out;
  char* ws = (char*)d_ws;

  // region A (16,777,216 B): xb then attn
  u16* xb   = (u16*)(ws + 0);
  u16* attn = (u16*)(ws + 0);
  // region B (50,331,648 B): qkv_wt then {qb, kb, vb, vt}
  char* B0 = ws + 16777216;
  u16* qkv_wt = (u16*)B0;
  u16* qbuf = (u16*)(B0 + 0);
  u16* kbuf = (u16*)(B0 + 16777216);
  u16* vbuf = (u16*)(B0 + 20971520);
  u16* vtb  = (u16*)(B0 + 25165824);
  // region C (33,554,432 B): qkv bf16 then o_wt
  char* C0 = ws + 67108864;
  u16* qkvb = (u16*)C0;
  u16* o_wt = (u16*)C0;

  // 1. cast x -> bf16
  k_cast_bf16<<<dim3((T_SEQ * HID / 4 + 255) / 256), 256, 0, stream>>>(x, xb, T_SEQ * HID / 4);
  // 2. transpose-cast qkv_w [4096][6144] -> [6144][4096] bf16
  k_transpose_cast<<<dim3(QKVN / 32, HID / 32), 256, 0, stream>>>(qkv_w, qkv_wt, HID, QKVN);
  // 3. qkv GEMM -> bf16 [T][6144]
  k_gemm_bt<QKVN, HID, u16><<<dim3(QKVN / 128, T_SEQ / 128), 256, 0, stream>>>(xb, qkv_wt, qkvb);
  // 4. rmsnorm + rope + split (overwrites region B; qkv_wt dead)
  k_normrope<<<dim3(T_SEQ, 12), 256, 0, stream>>>(qkvb, pos, qnw, knw, qbuf, kbuf, vbuf);
  // 5. V transpose [T][8][128] -> [8][128][T]
  k_transpose_v<<<dim3(T_SEQ / 32, HD / 32, NKV), 256, 0, stream>>>(vbuf, vtb);
  // 6. transpose-cast o_w -> [N][K] bf16 (overwrites region C; qkvb dead)
  k_transpose_cast<<<dim3(HID / 32, HID / 32), 256, 0, stream>>>(ow, o_wt, HID, HID);
  // 7. attention -> attn bf16 [T][4096] (overwrites region A; xb dead)
  k_attn<<<dim3(T_SEQ / 64, NH), 256, 0, stream>>>(qbuf, kbuf, vtb, attn);
  // 8. output GEMM -> fp32 d_out
  k_gemm_bt<HID, HID, float><<<dim3(HID / 128, T_SEQ / 128), 256, 0, stream>>>(attn, o_wt, out);
}

// Round 6
// 610.262 us; speedup vs baseline: 1.8356x; 1.8356x over previous
//
#include <hip/hip_runtime.h>
#include <hip/hip_bf16.h>

using u16 = unsigned short;
typedef __bf16 bf16x8 __attribute__((ext_vector_type(8)));
typedef float f32x4 __attribute__((ext_vector_type(4)));
typedef u16 u16x8 __attribute__((ext_vector_type(8)));
typedef u16 u16x4 __attribute__((ext_vector_type(4)));

constexpr int T_SEQ = 2048;
constexpr int HID   = 4096;
constexpr int NH    = 32;
constexpr int NKV   = 8;
constexpr int HD    = 128;
constexpr int QKVN  = 6144;   // 32*128 + 2*8*128

__device__ __forceinline__ u16 f2b(float x) {
  return __builtin_bit_cast(u16, __float2bfloat16(x));
}
__device__ __forceinline__ float b2f(u16 u) {
  return __builtin_bit_cast(float, (unsigned int)u << 16);
}
__device__ __forceinline__ bf16x8 load8(const u16* p) {
  return __builtin_bit_cast(bf16x8, *reinterpret_cast<const u16x8*>(p));
}
__device__ __forceinline__ f32x4 mfma16(bf16x8 a, bf16x8 b, f32x4 c) {
  return __builtin_amdgcn_mfma_f32_16x16x32_bf16(a, b, c, 0, 0, 0);
}

// ---------------- cast fp32 -> bf16 (vectorized) ----------------
__global__ __launch_bounds__(256) void k_cast_bf16(const float* __restrict__ in,
                                                   u16* __restrict__ out, int n4) {
  int i = blockIdx.x * 256 + threadIdx.x;
  if (i < n4) {
    float4 v = reinterpret_cast<const float4*>(in)[i];
    u16x4 o;
    o.x = f2b(v.x); o.y = f2b(v.y); o.z = f2b(v.z); o.w = f2b(v.w);
    reinterpret_cast<u16x4*>(out)[i] = o;
  }
}

// ---------------- transpose + cast: in[R][C] fp32 -> out[C][R] bf16 ----------------
__global__ __launch_bounds__(256) void k_transpose_cast(const float* __restrict__ in,
                                                        u16* __restrict__ out,
                                                        int R, int C) {
  __shared__ float tile[32][33];
  int cc = blockIdx.x << 5, rr = blockIdx.y << 5;
  int lx = threadIdx.x & 31, ly = threadIdx.x >> 5;
#pragma unroll
  for (int i = 0; i < 32; i += 8)
    tile[ly + i][lx] = in[(size_t)(rr + ly + i) * C + cc + lx];
  __syncthreads();
#pragma unroll
  for (int i = 0; i < 32; i += 8)
    out[(size_t)(cc + ly + i) * R + rr + lx] = f2b(tile[lx][ly + i]);
}

// ---------------- bf16 GEMM: C[M][N] = A[M][K] * B[N][K]^T ----------------
// 128x128 tile, BK=32, 4 waves (2x2 of 64x64), global_load_lds w16,
// XOR k-slot swizzle: LDS[row][slot] holds k-slot (slot ^ ((row>>1)&3)).
template <int N, int K, typename OutT>
__global__ __launch_bounds__(256) void k_gemm_bt(const u16* __restrict__ A,
                                                 const u16* __restrict__ B,
                                                 OutT* __restrict__ C) {
  __shared__ u16 lA[128 * 32];
  __shared__ u16 lB[128 * 32];
  const int tid = threadIdx.x;
  const int wid = tid >> 6, lane = tid & 63;
  const int row0 = blockIdx.y << 7, col0 = blockIdx.x << 7;
  const int wr = wid >> 1, wc = wid & 1;
  const int g = lane >> 4, c = lane & 15;

  f32x4 acc[4][4] = {};

  const int r_st = lane >> 2;      // row within 16-row wave chunk
  const int slot_st = lane & 3;    // 16B slot within 64B row

  const int rA0 = wr * 64 + c;
  const int rB0 = wc * 64 + c;
  const int swzA = (rA0 >> 1) & 3;  // invariant under +16 row steps
  const int swzB = (rB0 >> 1) & 3;

  for (int kt = 0; kt < K / 32; ++kt) {
    const int kk = kt * 32;
#pragma unroll
    for (int i = 0; i < 2; ++i) {
      int r = wid * 16 + i * 64 + r_st;
      int s = slot_st ^ ((r >> 1) & 3);
      const u16* ga = A + (size_t)(row0 + r) * K + kk + s * 8;
      const u16* gb = B + (size_t)(col0 + r) * K + kk + s * 8;
      char* la = (char*)lA + wid * 1024 + i * 4096;  // wave-uniform base
      char* lb = (char*)lB + wid * 1024 + i * 4096;
      __builtin_amdgcn_global_load_lds((const __attribute__((address_space(1))) void*)ga,
                                       (__attribute__((address_space(3))) void*)la, 16, 0, 0);
      __builtin_amdgcn_global_load_lds((const __attribute__((address_space(1))) void*)gb,
                                       (__attribute__((address_space(3))) void*)lb, 16, 0, 0);
    }
    __syncthreads();

    bf16x8 af[4], bfr[4];
#pragma unroll
    for (int m = 0; m < 4; ++m) {
      int row = rA0 + m * 16;
      af[m] = load8(lA + row * 32 + (g ^ swzA) * 8);
    }
#pragma unroll
    for (int n = 0; n < 4; ++n) {
      int row = rB0 + n * 16;
      bfr[n] = load8(lB + row * 32 + (g ^ swzB) * 8);
    }
#pragma unroll
    for (int m = 0; m < 4; ++m)
#pragma unroll
      for (int n = 0; n < 4; ++n)
        acc[m][n] = mfma16(af[m], bfr[n], acc[m][n]);
    __syncthreads();
  }

  // epilogue: D layout col=lane&15, row=(lane>>4)*4+reg  (m89-verified)
#pragma unroll
  for (int m = 0; m < 4; ++m) {
    int grow0 = row0 + wr * 64 + m * 16 + g * 4;
#pragma unroll
    for (int n = 0; n < 4; ++n) {
      int gcol = col0 + wc * 64 + n * 16 + c;
#pragma unroll
      for (int j = 0; j < 4; ++j) {
        float v = acc[m][n][j];
        if constexpr (sizeof(OutT) == 2)
          C[(size_t)(grow0 + j) * N + gcol] = f2b(v);
        else
          C[(size_t)(grow0 + j) * N + gcol] = v;
      }
    }
  }
}

// ---------------- fused per-head RMSNorm + RoPE + scale, qkv split ----------------
__global__ __launch_bounds__(256) void k_normrope(const u16* __restrict__ qkv,
                                                  const int* __restrict__ pos,
                                                  const float* __restrict__ qw,
                                                  const float* __restrict__ kw,
                                                  u16* __restrict__ qo,
                                                  u16* __restrict__ ko,
                                                  u16* __restrict__ vo) {
  int t = blockIdx.x;
  int wid = threadIdx.x >> 6, lane = threadIdx.x & 63;
  int h = blockIdx.y * 4 + wid;  // 0..47
  const u16* src = qkv + (size_t)t * QKVN + h * HD;
  float x1 = b2f(src[lane]), x2 = b2f(src[lane + 64]);
  float ss = x1 * x1 + x2 * x2;
#pragma unroll
  for (int m = 1; m < 64; m <<= 1) ss += __shfl_xor(ss, m);
  float sc = rsqrtf(ss * (1.0f / HD) + 1e-6f);
  if (h < 40) {
    const float* w = (h < NH) ? qw : kw;
    float y1 = x1 * sc * w[lane], y2 = x2 * sc * w[lane + 64];
    float p = (float)pos[t];
    // inv_freq = 10000^(-lane/64) = exp2(-lane * log2(10000)/64)
    float inv = exp2f((float)lane * (-13.287712379549449f / 64.0f));
    float ang = p * inv;
    float sn, cs;
    sincosf(ang, &sn, &cs);
    float o1 = y1 * cs - y2 * sn;
    float o2 = y2 * cs + y1 * sn;
    if (h < NH) {
      o1 *= 0.08838834764831845f;  // fold 1/sqrt(128) into q
      o2 *= 0.08838834764831845f;
      u16* dst = qo + ((size_t)t * NH + h) * HD;
      dst[lane] = f2b(o1);
      dst[lane + 64] = f2b(o2);
    } else {
      u16* dst = ko + ((size_t)t * NKV + (h - NH)) * HD;
      dst[lane] = f2b(o1);
      dst[lane + 64] = f2b(o2);
    }
  } else {
    u16* dst = vo + ((size_t)t * NKV + (h - 40)) * HD;
    dst[lane] = f2b(x1);
    dst[lane + 64] = f2b(x2);
  }
}

// ---------------- V transpose: vb[T][NKV][HD] -> vt[NKV][HD][T] ----------------
__global__ __launch_bounds__(256) void k_transpose_v(const u16* __restrict__ vb,
                                                     u16* __restrict__ vt) {
  __shared__ u16 tile[32][33];
  int tt = blockIdx.x << 5, dd = blockIdx.y << 5, h = blockIdx.z;
  int lx = threadIdx.x & 31, ly = threadIdx.x >> 5;
#pragma unroll
  for (int i = 0; i < 32; i += 8)
    tile[ly + i][lx] = vb[((size_t)(tt + ly + i) * NKV + h) * HD + dd + lx];
  __syncthreads();
#pragma unroll
  for (int i = 0; i < 32; i += 8)
    vt[((size_t)h * HD + dd + ly + i) * T_SEQ + tt + lx] = tile[lx][ly + i];
}

// ---------------- flash attention v3: LDS-staged K/V, swapped QK^T softmax ----------------
// Block = (64-row q-group, head), 4 waves each owning 16 q-rows. KVBLK=64.
// K/V tiles staged via coalesced global_load_lds, double-buffered, shared by
// all 4 waves (same head). 16B-slot XOR swizzle (K: ^row&15, V: ^d&7) applied
// on both source addressing and LDS reads (rule #21).
__global__ __launch_bounds__(256) void k_attn(const u16* __restrict__ qb,
                                              const u16* __restrict__ kbg,
                                              const u16* __restrict__ vtg,
                                              u16* __restrict__ out) {
  __shared__ u16 sK[2][64 * 128];   // [kv 64][hd 128], 256B rows, swz slot^(row&15)
  __shared__ u16 sV[2][128 * 64];   // [d 128][kv 64], 128B rows, swz slot^(d&7)
  const int wid = threadIdx.x >> 6, lane = threadIdx.x & 63;
  const int h = blockIdx.y, hk = h >> 2;
  const int qt = gridDim.x - 1 - blockIdx.x;   // longest blocks launch first
  const int ntiles = qt + 1;
  const int qb0 = qt * 64 + wid * 16;
  const int g = lane >> 4, c = lane & 15;

  // staging: 16 K-instrs + 16 V-instrs per tile, split 4+4 per wave
  auto stage = [&](int buf, int kvb) {
#pragma unroll
    for (int ii = 0; ii < 4; ++ii) {
      int i = wid * 4 + ii;
      {  // K: lane -> row r = i*4 + (lane>>4), slot = lane&15
        int r = i * 4 + (lane >> 4);
        int slot = lane & 15;
        const u16* src = kbg + ((size_t)(kvb + r) * NKV + hk) * HD + ((slot ^ (r & 15)) * 8);
        __builtin_amdgcn_global_load_lds((const __attribute__((address_space(1))) void*)src,
                                         (__attribute__((address_space(3))) void*)((char*)sK[buf] + i * 1024),
                                         16, 0, 0);
      }
      {  // V: lane -> row d = i*8 + (lane>>3), slot3 = lane&7
        int d = i * 8 + (lane >> 3);
        int slot3 = lane & 7;
        const u16* src = vtg + ((size_t)hk * HD + d) * T_SEQ + kvb + ((slot3 ^ (d & 7)) * 8);
        __builtin_amdgcn_global_load_lds((const __attribute__((address_space(1))) void*)src,
                                         (__attribute__((address_space(3))) void*)((char*)sV[buf] + i * 1024),
                                         16, 0, 0);
      }
    }
  };

  // Q fragments once (B-operand): B[col=q=c][hd-slot (g,e)]
  bf16x8 qf[4];
  const u16* qrow = qb + ((size_t)(qb0 + c) * NH + h) * HD;
#pragma unroll
  for (int kc = 0; kc < 4; ++kc) qf[kc] = load8(qrow + kc * 32 + g * 8);

  f32x4 accO[8] = {};           // accO[c2][j] = O[q=qb0+4g+j][d=c2*16+c]
  float m_ = -1e30f, l_ = 0.f;  // running max/sum for q = qb0 + c
  const int tq = qb0 + c;

  // V read element offsets (u16 units) within a swizzled 128B d-row; d&7 == c&7
  const int gh = g >> 1, gl4 = 4 * (g & 1), cx = c & 7;
  const int e0 = ((0 + gh) ^ cx) * 8 + gl4;   // kv 4g..4g+3
  const int e1 = ((2 + gh) ^ cx) * 8 + gl4;   // kv 16+4g..
  const int e2 = ((4 + gh) ^ cx) * 8 + gl4;   // kv 32+4g..
  const int e3 = ((6 + gh) ^ cx) * 8 + gl4;   // kv 48+4g..

  stage(0, 0);
  __syncthreads();

  for (int kt = 0; kt < ntiles; ++kt) {
    const int kvb = kt * 64;
    const int cur = kt & 1;
    if (kt + 1 < ntiles) stage(cur ^ 1, kvb + 64);

    // QK^T from LDS K-tile: s[tt][j] = S[k=kvb+tt*16+4g+j][q=qb0+c]
    f32x4 s[4];
#pragma unroll
    for (int tt = 0; tt < 4; ++tt) {
      const u16* kr = sK[cur] + (tt * 16 + c) * 128;
      f32x4 st = {0.f, 0.f, 0.f, 0.f};
#pragma unroll
      for (int kc = 0; kc < 4; ++kc) {
        int slot = (kc * 4 + g) ^ c;   // row&15 == c
        st = mfma16(load8(kr + slot * 8), qf[kc], st);
      }
      s[tt] = st;
    }

    // causal mask + row max (q fixed per lane)
    float vmax = -1e30f;
#pragma unroll
    for (int tt = 0; tt < 4; ++tt)
#pragma unroll
      for (int j = 0; j < 4; ++j) {
        int tk = kvb + tt * 16 + 4 * g + j;
        float v = (tk <= tq) ? s[tt][j] : -1e30f;
        s[tt][j] = v;
        vmax = fmaxf(vmax, v);
      }
    vmax = fmaxf(vmax, __shfl_xor(vmax, 16));
    vmax = fmaxf(vmax, __shfl_xor(vmax, 32));
    float mn = fmaxf(m_, vmax);
    float a = __expf(m_ - mn);
    float ps = 0.f;
#pragma unroll
    for (int tt = 0; tt < 4; ++tt)
#pragma unroll
      for (int j = 0; j < 4; ++j) {
        float p = __expf(s[tt][j] - mn);
        s[tt][j] = p;
        ps += p;
      }
    ps += __shfl_xor(ps, 16);
    ps += __shfl_xor(ps, 32);
    l_ = l_ * a + ps;
    m_ = mn;

    // rescale accO (q = 4g+j lives at lane c=4g+j)
    float aq[4];
#pragma unroll
    for (int j = 0; j < 4; ++j) aq[j] = __shfl(a, 20 * g + j);
#pragma unroll
    for (int c2 = 0; c2 < 8; ++c2)
#pragma unroll
      for (int j = 0; j < 4; ++j) accO[c2][j] *= aq[j];

    // pack P^T into two A-fragments: frag0 = kv[0..31], frag1 = kv[32..63]
    u16x8 p0u, p1u;
#pragma unroll
    for (int j = 0; j < 4; ++j) {
      p0u[j]     = f2b(s[0][j]);
      p0u[j + 4] = f2b(s[1][j]);
      p1u[j]     = f2b(s[2][j]);
      p1u[j + 4] = f2b(s[3][j]);
    }
    bf16x8 p0 = __builtin_bit_cast(bf16x8, p0u);
    bf16x8 p1 = __builtin_bit_cast(bf16x8, p1u);

    // PV from LDS V-tile: V slots match P's k placement
#pragma unroll
    for (int c2 = 0; c2 < 8; ++c2) {
      const u16* vr = sV[cur] + (c2 * 16 + c) * 64;
      u16x4 va  = *reinterpret_cast<const u16x4*>(vr + e0);
      u16x4 vb4 = *reinterpret_cast<const u16x4*>(vr + e1);
      u16x4 vc4 = *reinterpret_cast<const u16x4*>(vr + e2);
      u16x4 vd  = *reinterpret_cast<const u16x4*>(vr + e3);
      u16x8 v0u, v1u;
#pragma unroll
      for (int j = 0; j < 4; ++j) {
        v0u[j] = va[j];  v0u[j + 4] = vb4[j];
        v1u[j] = vc4[j]; v1u[j + 4] = vd[j];
      }
      accO[c2] = mfma16(p0, __builtin_bit_cast(bf16x8, v0u), accO[c2]);
      accO[c2] = mfma16(p1, __builtin_bit_cast(bf16x8, v1u), accO[c2]);
    }

    __syncthreads();  // drains staging vmcnt; protects both buffers
  }

  // epilogue: divide by l (q = 4g+j via shuffle) and store
  float lq[4];
#pragma unroll
  for (int j = 0; j < 4; ++j) lq[j] = 1.0f / __shfl(l_, 20 * g + j);
#pragma unroll
  for (int c2 = 0; c2 < 8; ++c2)
#pragma unroll
    for (int j = 0; j < 4; ++j) {
      float o = accO[c2][j] * lq[j];
      out[(size_t)(qb0 + 4 * g + j) * HID + h * HD + c2 * 16 + c] = f2b(o);
    }
}

// ---------------- launch ----------------
extern "C" void kernel_launch(void* const* d_in, const int* in_sizes, int n_in,
                              void* d_out, int out_size, void* d_ws, size_t ws_size,
                              hipStream_t stream) {
  (void)in_sizes; (void)n_in; (void)out_size; (void)ws_size;
  const float* x      = (const float*)d_in[0];
  const int*   pos    = (const int*)d_in[1];
  const float* qkv_w  = (const float*)d_in[2];
  const float* qnw    = (const float*)d_in[3];
  const float* knw    = (const float*)d_in[4];
  const float* ow     = (const float*)d_in[5];
  float* out = (float*)d_out;
  char* ws = (char*)d_ws;

  // region A (16,777,216 B): xb then attn
  u16* xb   = (u16*)(ws + 0);
  u16* attn = (u16*)(ws + 0);
  // region B (50,331,648 B): qkv_wt then {qb, kb, vb, vt}
  char* B0 = ws + 16777216;
  u16* qkv_wt = (u16*)B0;
  u16* qbuf = (u16*)(B0 + 0);
  u16* kbuf = (u16*)(B0 + 16777216);
  u16* vbuf = (u16*)(B0 + 20971520);
  u16* vtb  = (u16*)(B0 + 25165824);
  // region C (33,554,432 B): qkv bf16 then o_wt
  char* C0 = ws + 67108864;
  u16* qkvb = (u16*)C0;
  u16* o_wt = (u16*)C0;

  // 1. cast x -> bf16
  k_cast_bf16<<<dim3((T_SEQ * HID / 4 + 255) / 256), 256, 0, stream>>>(x, xb, T_SEQ * HID / 4);
  // 2. transpose-cast qkv_w [4096][6144] -> [6144][4096] bf16
  k_transpose_cast<<<dim3(QKVN / 32, HID / 32), 256, 0, stream>>>(qkv_w, qkv_wt, HID, QKVN);
  // 3. qkv GEMM -> bf16 [T][6144]
  k_gemm_bt<QKVN, HID, u16><<<dim3(QKVN / 128, T_SEQ / 128), 256, 0, stream>>>(xb, qkv_wt, qkvb);
  // 4. rmsnorm + rope + split (overwrites region B; qkv_wt dead)
  k_normrope<<<dim3(T_SEQ, 12), 256, 0, stream>>>(qkvb, pos, qnw, knw, qbuf, kbuf, vbuf);
  // 5. V transpose [T][8][128] -> [8][128][T]
  k_transpose_v<<<dim3(T_SEQ / 32, HD / 32, NKV), 256, 0, stream>>>(vbuf, vtb);
  // 6. transpose-cast o_w -> [N][K] bf16 (overwrites region C; qkvb dead)
  k_transpose_cast<<<dim3(HID / 32, HID / 32), 256, 0, stream>>>(ow, o_wt, HID, HID);
  // 7. attention -> attn bf16 [T][4096] (overwrites region A; xb dead)
  k_attn<<<dim3(T_SEQ / 64, NH), 256, 0, stream>>>(qbuf, kbuf, vtb, attn);
  // 8. output GEMM -> fp32 d_out
  k_gemm_bt<HID, HID, float><<<dim3(HID / 128, T_SEQ / 128), 256, 0, stream>>>(attn, o_wt, out);
}